// Round 14
// baseline (243.941 us; speedup 1.0000x reference)
//
#include <hip/hip_runtime.h>
#include <stdint.h>
#include <math.h>

#define HW_ 16384   // H*W = 128*128
#define C_  256
#define NT  2       // tiles per block (each tile = 256 positions)

typedef long i64;
typedef float f32x4 __attribute__((ext_vector_type(4)));
typedef unsigned int u32;
typedef unsigned long long u64;

// -------- kernel 0: prep (W -> fp8 e4m3 in MFMA-fragment order, BN consts) --
// Wp byte layout: idx = ((ks*16 + mf)*64 + kg*16 + r15)*8 + e
__global__ __launch_bounds__(256) void k0_prep(
    const float* __restrict__ w_fe, const float* __restrict__ gamma,
    const float* __restrict__ beta, const float* __restrict__ mean,
    const float* __restrict__ var, u32* __restrict__ Wp,
    float* __restrict__ scale, float* __restrict__ shift)
{
  int i = blockIdx.x * 256 + threadIdx.x;
  if (i < 32768) {                     // one u32 = 4 fp8 bytes
    int e0  = (i & 1) * 4;
    int r15 = (i >> 1) & 15;
    int kg  = (i >> 5) & 3;
    int mf  = (i >> 7) & 15;
    int ks  = i >> 11;
    int row = mf * 16 + r15;
    int k   = ks * 32 + kg * 8 + e0;   // 4 consecutive k
    const float* src = w_fe + row * 512 + k;
    u32 w = 0;
    w = __builtin_amdgcn_cvt_pk_fp8_f32(src[0], src[1], w, false);
    w = __builtin_amdgcn_cvt_pk_fp8_f32(src[2], src[3], w, true);
    Wp[i] = w;
  }
  if (i < 256) {
    float sc = gamma[i] * rsqrtf(var[i] + 1e-5f);
    scale[i] = sc;
    shift[i] = beta[i] - mean[i] * sc;
  }
}

// ------- kernel 1: persistent-W fp8 MFMA GEMM + BN + ReLU + pool -------
// 16 waves; wave w = m-frag w (16 ch). Tile = 256 pos x 512 k fp8, single
// 128-KB LDS buffer. STAGING IS 1KB-CONTIGUOUS PER WAVE-LOAD (the k3
// pattern): each instruction reads one k-row's 256 pos (64 lanes x float4).
// Per 8-row group: thread holds rows j=0..7 at pos[4L..4L+3] -> cvt_pk ->
// 4 ds_write_b64 (e-contiguous). LDS slot swizzle: phys = p ^ ((p>>4)&3)
// ^ ((ko&3)<<4)  -> floor-rate writes, conflict-free frag reads.
// Compute: 2 passes of 8 nf (acc 32 regs), full K resident -> exact BN/ReLU.
__global__ __launch_bounds__(1024, 4) void k1_gemm_pool(
    const float* __restrict__ x1, const float* __restrict__ x2,
    const u32* __restrict__ Wp,
    const float* __restrict__ scale, const float* __restrict__ shift,
    float* __restrict__ pool_part)
{
  __shared__ __align__(16) char Bl[131072];   // 64 rows-of-8k x 2048 B

  const int tid  = threadIdx.x;
  const int wave = tid >> 6;        // = mf
  const int lane = tid & 63;
  const int r15  = lane & 15;
  const int kg   = lane >> 4;
  const int blk  = blockIdx.x;
  const int b    = blk >> 5;                 // batch
  const int jp   = blk & 31;                 // tile-pair index

  const float* xb1 = x1 + (size_t)b * C_ * HW_;
  const float* xb2 = x2 + (size_t)b * C_ * HW_;

  // ---- A-frags once for this wave (16 x i64 = 32 regs) ----
  i64 Af[16];
#pragma unroll
  for (int ks = 0; ks < 16; ++ks)
    Af[ks] = *(const i64*)((const char*)Wp
             + ((ks * 16 + wave) * 64 + kg * 16 + r15) * 8);

  const int chbase = wave * 16 + kg * 4;
  const float4 sc4 = *(const float4*)&scale[chbase];
  const float4 sh4 = *(const float4*)&shift[chbase];

  float pool0 = 0.f, pool1 = 0.f, pool2 = 0.f, pool3 = 0.f;

  for (int tt = 0; tt < NT; ++tt) {
    const int P0 = (jp * NT + tt) * 256;   // tile base position

    // ================= FILL: 512 rows x 1KB contiguous wave-loads ========
#pragma unroll
    for (int gi = 0; gi < 4; ++gi) {
      const int G = wave + gi * 16;        // row-octet 0..63
      const float* src = ((G < 32) ? (xb1 + (size_t)(G * 8) * HW_)
                                   : (xb2 + (size_t)(G - 32) * 8 * HW_))
                         + P0 + lane * 4;
      f32x4 g[8];
#pragma unroll
      for (int j = 0; j < 8; ++j) g[j] = *(const f32x4*)(src + (size_t)j * HW_);
      char* rowb = Bl + G * 2048;
#pragma unroll
      for (int q2 = 0; q2 < 4; ++q2) {
        u32 w0 = 0, w1 = 0;
        w0 = __builtin_amdgcn_cvt_pk_fp8_f32(g[0][q2], g[1][q2], w0, false);
        w0 = __builtin_amdgcn_cvt_pk_fp8_f32(g[2][q2], g[3][q2], w0, true);
        w1 = __builtin_amdgcn_cvt_pk_fp8_f32(g[4][q2], g[5][q2], w1, false);
        w1 = __builtin_amdgcn_cvt_pk_fp8_f32(g[6][q2], g[7][q2], w1, true);
        int p  = lane * 4 + q2;
        int sl = p ^ ((p >> 4) & 3) ^ ((G & 3) << 4);
        u64 v = (u64)w0 | ((u64)w1 << 32);   // bytes e0..e7
        *(u64*)(rowb + sl * 8) = v;
      }
    }
    __syncthreads();   // tile staged

    // ================= COMPUTE: 2 passes x (16 ks x 8 nf) ================
#pragma unroll
    for (int pass = 0; pass < 2; ++pass) {
      f32x4 acc[8];
#pragma unroll
      for (int f = 0; f < 8; ++f) acc[f] = (f32x4){0.f, 0.f, 0.f, 0.f};
#pragma unroll
      for (int ks = 0; ks < 16; ++ks) {
        const char* kb = Bl + ks * 8192 + kg * 2048;
#pragma unroll
        for (int f = 0; f < 8; ++f) {
          const int nf = pass * 8 + f;
          const int sl = (((nf ^ kg) & 15) << 4) | (r15 ^ (nf & 3));
          i64 bq = *(const i64*)(kb + sl * 8);
          acc[f] = __builtin_amdgcn_mfma_f32_16x16x32_fp8_fp8(
              Af[ks], bq, acc[f], 0, 0, 0);
        }
      }
      // BN + ReLU + pool over these 128 positions
#pragma unroll
      for (int f = 0; f < 8; ++f) {
        pool0 += fmaxf(acc[f][0] * sc4.x + sh4.x, 0.f);
        pool1 += fmaxf(acc[f][1] * sc4.y + sh4.y, 0.f);
        pool2 += fmaxf(acc[f][2] * sc4.z + sh4.z, 0.f);
        pool3 += fmaxf(acc[f][3] * sc4.w + sh4.w, 0.f);
      }
    }
    __syncthreads();   // all waves done reading before next fill
  }

  // reduce over the 16 positions (r15 lanes)
#pragma unroll
  for (int m = 1; m < 16; m <<= 1) {
    pool0 += __shfl_xor(pool0, m);
    pool1 += __shfl_xor(pool1, m);
    pool2 += __shfl_xor(pool2, m);
    pool3 += __shfl_xor(pool3, m);
  }
  if (r15 == 0) {
    float* dst = pool_part + (size_t)blk * 256 + chbase;
    dst[0] = pool0; dst[1] = pool1; dst[2] = pool2; dst[3] = pool3;
  }
}

// -------- kernel 2: tiny MLPs -> per-(b,c) 3x3 kernels + attn coefs --------
// grid 80 = 8 batches x 10 jobs (j=0..8: tap j of all 256 channels; j=9: coef)
__global__ __launch_bounds__(256) void k2_small(
    const float* __restrict__ pool_part,
    const float* __restrict__ w_cg1, const float* __restrict__ w_cg2,
    const float* __restrict__ w_ag1, const float* __restrict__ w_ag2,
    float* __restrict__ cw, float* __restrict__ coef)
{
  __shared__ float pl[256];
  __shared__ float hl[64];
  const int bi = blockIdx.x;
  const int b = bi / 10, j = bi % 10;
  const int t = threadIdx.x;
  float s = 0.f;
  const float* base = pool_part + (size_t)b * 32 * 256 + t;
  for (int blk = 0; blk < 32; ++blk) s += base[blk * 256];   // fixed order
  pl[t] = s * (1.0f / 16384.0f);
  __syncthreads();
  if (j < 9) {
    if (t < 64) {
      float h = 0.f;
      for (int i = 0; i < 256; ++i) h += pl[i] * w_cg1[t * 256 + i];
      hl[t] = fmaxf(h, 0.f);
    }
    __syncthreads();
    const int o = t * 9 + j;                 // row of w_cg2 = c*9 + tap
    float acc = 0.f;
    for (int jj = 0; jj < 64; ++jj) acc += hl[jj] * w_cg2[o * 64 + jj];
    cw[b * 2304 + o] = acc;
  } else {
    if (t < 64) {
      float a = 0.f;
      for (int i = 0; i < 256; ++i) a += pl[i] * w_ag1[t * 256 + i];
      hl[t] = fmaxf(a, 0.f);
    }
    __syncthreads();
    if (t < 2) {
      float acc = 0.f;
      for (int jj = 0; jj < 64; ++jj) acc += hl[jj] * w_ag2[t * 64 + jj];
      coef[b * 2 + t] = 0.25f / (1.0f + expf(-acc));   // 0.25 = L_S * L_C
    }
  }
}

// -------- kernel 3: depthwise 3x3 (same kernel on x1 & x2) + combine --------
__global__ __launch_bounds__(256) void k3_dynconv(
    const float* __restrict__ x1, const float* __restrict__ x2,
    const float* __restrict__ cw, const float* __restrict__ coef,
    float* __restrict__ out)
{
  __shared__ float t1[34 * 128];
  __shared__ float t2[34 * 128];
  const int tid   = threadIdx.x;
  const int blk   = blockIdx.x;
  const int strip = blk & 3;
  const int c     = (blk >> 2) & 255;
  const int b     = blk >> 10;
  const int h0    = strip * 32;

  const size_t plane = ((size_t)b * C_ + c) * HW_;
  const float* p1 = x1 + plane;
  const float* p2 = x2 + plane;

  float tp[9];
#pragma unroll
  for (int e = 0; e < 9; ++e) tp[e] = cw[(b * C_ + c) * 9 + e];
  const float c1 = coef[b * 2 + 0];
  const float c2 = coef[b * 2 + 1];

  for (int f = tid; f < 1088; f += 256) {
    int row = f >> 5;
    int c4  = (f & 31) << 2;
    int gh  = h0 - 1 + row;
    float4 v1 = make_float4(0.f, 0.f, 0.f, 0.f), v2 = v1;
    if (gh >= 0 && gh < 128) {
      v1 = *(const float4*)&p1[gh * 128 + c4];
      v2 = *(const float4*)&p2[gh * 128 + c4];
    }
    *(float4*)&t1[row * 128 + c4] = v1;
    *(float4*)&t2[row * 128 + c4] = v2;
  }
  __syncthreads();

  for (int i = 0; i < 16; ++i) {
    int q   = tid + i * 256;
    int r   = q >> 7;
    int col = q & 127;
    int lr  = r + 1;
    const bool lok = col > 0, rok = col < 127;
    float d1 = 0.f, d2 = 0.f;
#pragma unroll
    for (int dy = 0; dy < 3; ++dy) {
      const float* row1 = &t1[(lr - 1 + dy) * 128];
      const float* row2 = &t2[(lr - 1 + dy) * 128];
      float a1v = lok ? row1[col - 1] : 0.f;
      float b1v = row1[col];
      float e1v = rok ? row1[col + 1] : 0.f;
      float a2v = lok ? row2[col - 1] : 0.f;
      float b2v = row2[col];
      float e2v = rok ? row2[col + 1] : 0.f;
      d1 += a1v * tp[dy * 3 + 0] + b1v * tp[dy * 3 + 1] + e1v * tp[dy * 3 + 2];
      d2 += a2v * tp[dy * 3 + 0] + b2v * tp[dy * 3 + 1] + e2v * tp[dy * 3 + 2];
    }
    float v1 = t1[lr * 128 + col];
    float v2 = t2[lr * 128 + col];
    out[plane + (size_t)(h0 + r) * 128 + col] = 0.5f * (v1 + v2) + c1 * d1 + c2 * d2;
  }
}

extern "C" void kernel_launch(void* const* d_in, const int* in_sizes, int n_in,
                              void* d_out, int out_size, void* d_ws, size_t ws_size,
                              hipStream_t stream) {
  const float* x1    = (const float*)d_in[0];
  const float* x2    = (const float*)d_in[1];
  const float* w_fe  = (const float*)d_in[2];
  const float* gamma = (const float*)d_in[3];
  const float* beta  = (const float*)d_in[4];
  const float* mean  = (const float*)d_in[5];
  const float* var   = (const float*)d_in[6];
  const float* w_cg1 = (const float*)d_in[7];
  const float* w_cg2 = (const float*)d_in[8];
  const float* w_ag1 = (const float*)d_in[9];
  const float* w_ag2 = (const float*)d_in[10];
  float* out = (float*)d_out;

  // workspace layout (~470 KB)
  char* ws = (char*)d_ws;
  u32* Wp          = (u32*)(ws);                           // [0, 131072)
  float* scale     = (float*)(ws + 131072);                // 1 KB
  float* shift     = (float*)(ws + 132096);                // 1 KB
  float* pool_part = (float*)(ws + 133120);                // 256*256*4 = 256 KB
  float* cw        = (float*)(ws + 395264);                // 73728 B
  float* coef      = (float*)(ws + 468992);                // 64 B

  k0_prep<<<128, 256, 0, stream>>>(w_fe, gamma, beta, mean, var, Wp, scale, shift);
  k1_gemm_pool<<<256, 1024, 0, stream>>>(x1, x2, Wp, scale, shift, pool_part);
  k2_small<<<80, 256, 0, stream>>>(pool_part, w_cg1, w_cg2, w_ag1, w_ag2, cw, coef);
  k3_dynconv<<<8192, 256, 0, stream>>>(x1, x2, cw, coef, out);
}

// Round 15
// 242.505 us; speedup vs baseline: 1.0059x; 1.0059x over previous
//
#include <hip/hip_runtime.h>
#include <stdint.h>
#include <math.h>

#define HW_ 16384   // H*W = 128*128
#define C_  256
#define NT  2       // tiles per block (each tile = 256 positions)

typedef long i64;
typedef float f32x4 __attribute__((ext_vector_type(4)));
typedef unsigned int u32;
typedef unsigned long long u64;

// -------- kernel 0: prep (W -> fp8 e4m3 in MFMA-fragment order, BN consts) --
// Wp byte layout: idx = ((ks*16 + mf)*64 + kg*16 + r15)*8 + e
__global__ __launch_bounds__(256) void k0_prep(
    const float* __restrict__ w_fe, const float* __restrict__ gamma,
    const float* __restrict__ beta, const float* __restrict__ mean,
    const float* __restrict__ var, u32* __restrict__ Wp,
    float* __restrict__ scale, float* __restrict__ shift)
{
  int i = blockIdx.x * 256 + threadIdx.x;
  if (i < 32768) {                     // one u32 = 4 fp8 bytes
    int e0  = (i & 1) * 4;
    int r15 = (i >> 1) & 15;
    int kg  = (i >> 5) & 3;
    int mf  = (i >> 7) & 15;
    int ks  = i >> 11;
    int row = mf * 16 + r15;
    int k   = ks * 32 + kg * 8 + e0;   // 4 consecutive k
    const float* src = w_fe + row * 512 + k;
    u32 w = 0;
    w = __builtin_amdgcn_cvt_pk_fp8_f32(src[0], src[1], w, false);
    w = __builtin_amdgcn_cvt_pk_fp8_f32(src[2], src[3], w, true);
    Wp[i] = w;
  }
  if (i < 256) {
    float sc = gamma[i] * rsqrtf(var[i] + 1e-5f);
    scale[i] = sc;
    shift[i] = beta[i] - mean[i] * sc;
  }
}

// ------- kernel 1: persistent-W fp8 MFMA GEMM + BN + ReLU + pool -------
// Identical to R14 EXCEPT the FILL loop register lifetime: #pragma unroll 1
// + sched_barrier(0) per iteration pins ONE g[8] (32 regs) live instead of
// the hoisted 4x128 that spilled. Each wave-load is ONE 1-KB CONTIGUOUS
// segment (64 lanes x 16 B, single k-row) -- the granularity experiment,
// now spill-free. Tile = 256 pos x 512 k fp8, single 128-KB LDS buffer,
// serial stage->compute, 2 tiles/block, grid 256.
__global__ __launch_bounds__(1024, 4) void k1_gemm_pool(
    const float* __restrict__ x1, const float* __restrict__ x2,
    const u32* __restrict__ Wp,
    const float* __restrict__ scale, const float* __restrict__ shift,
    float* __restrict__ pool_part)
{
  __shared__ __align__(16) char Bl[131072];   // 64 row-octets x 2048 B

  const int tid  = threadIdx.x;
  const int wave = tid >> 6;        // = mf
  const int lane = tid & 63;
  const int r15  = lane & 15;
  const int kg   = lane >> 4;
  const int blk  = blockIdx.x;
  const int b    = blk >> 5;                 // batch
  const int jp   = blk & 31;                 // tile-pair index

  const float* xb1 = x1 + (size_t)b * C_ * HW_;
  const float* xb2 = x2 + (size_t)b * C_ * HW_;

  // ---- A-frags once for this wave (16 x i64 = 32 regs) ----
  i64 Af[16];
#pragma unroll
  for (int ks = 0; ks < 16; ++ks)
    Af[ks] = *(const i64*)((const char*)Wp
             + ((ks * 16 + wave) * 64 + kg * 16 + r15) * 8);

  const int chbase = wave * 16 + kg * 4;
  const float4 sc4 = *(const float4*)&scale[chbase];
  const float4 sh4 = *(const float4*)&shift[chbase];

  float pool0 = 0.f, pool1 = 0.f, pool2 = 0.f, pool3 = 0.f;

  for (int tt = 0; tt < NT; ++tt) {
    const int P0 = (jp * NT + tt) * 256;   // tile base position

    // ========== FILL: 512 rows x 1-KB contiguous wave-loads =============
    // unroll 1 + sched_barrier: exactly one g[8] (32 regs) live at a time.
#pragma unroll 1
    for (int gi = 0; gi < 4; ++gi) {
      const int G = wave + gi * 16;        // row-octet 0..63
      const float* src = ((G < 32) ? (xb1 + (size_t)(G * 8) * HW_)
                                   : (xb2 + (size_t)((G - 32) * 8) * HW_))
                         + P0 + lane * 4;
      f32x4 g[8];
#pragma unroll
      for (int j = 0; j < 8; ++j) g[j] = *(const f32x4*)(src + (size_t)j * HW_);
      char* rowb = Bl + G * 2048;
#pragma unroll
      for (int q2 = 0; q2 < 4; ++q2) {
        u32 w0 = 0, w1 = 0;
        w0 = __builtin_amdgcn_cvt_pk_fp8_f32(g[0][q2], g[1][q2], w0, false);
        w0 = __builtin_amdgcn_cvt_pk_fp8_f32(g[2][q2], g[3][q2], w0, true);
        w1 = __builtin_amdgcn_cvt_pk_fp8_f32(g[4][q2], g[5][q2], w1, false);
        w1 = __builtin_amdgcn_cvt_pk_fp8_f32(g[6][q2], g[7][q2], w1, true);
        int p  = lane * 4 + q2;
        int sl = p ^ ((p >> 4) & 3) ^ ((G & 3) << 4);
        u64 v = (u64)w0 | ((u64)w1 << 32);   // bytes e0..e7
        *(u64*)(rowb + sl * 8) = v;
      }
      __builtin_amdgcn_sched_barrier(0);     // no cross-iteration hoisting
    }
    __syncthreads();   // tile staged

    // ========== COMPUTE: 2 passes x (16 ks x 8 nf) ======================
    // read slot decodes to logical pos = nf*16 + r15 (kg-independent);
    // verified bijective & K-consistent (R14 algebra audit).
#pragma unroll
    for (int pass = 0; pass < 2; ++pass) {
      f32x4 acc[8];
#pragma unroll
      for (int f = 0; f < 8; ++f) acc[f] = (f32x4){0.f, 0.f, 0.f, 0.f};
#pragma unroll
      for (int ks = 0; ks < 16; ++ks) {
        const char* kb = Bl + ks * 8192 + kg * 2048;
#pragma unroll
        for (int f = 0; f < 8; ++f) {
          const int nf = pass * 8 + f;
          const int sl = (((nf ^ kg) & 15) << 4) | (r15 ^ (nf & 3));
          i64 bq = *(const i64*)(kb + sl * 8);
          acc[f] = __builtin_amdgcn_mfma_f32_16x16x32_fp8_fp8(
              Af[ks], bq, acc[f], 0, 0, 0);
        }
      }
      // BN + ReLU + pool over these 128 positions
#pragma unroll
      for (int f = 0; f < 8; ++f) {
        pool0 += fmaxf(acc[f][0] * sc4.x + sh4.x, 0.f);
        pool1 += fmaxf(acc[f][1] * sc4.y + sh4.y, 0.f);
        pool2 += fmaxf(acc[f][2] * sc4.z + sh4.z, 0.f);
        pool3 += fmaxf(acc[f][3] * sc4.w + sh4.w, 0.f);
      }
    }
    __syncthreads();   // all waves done reading before next fill
  }

  // reduce over the 16 positions (r15 lanes)
#pragma unroll
  for (int m = 1; m < 16; m <<= 1) {
    pool0 += __shfl_xor(pool0, m);
    pool1 += __shfl_xor(pool1, m);
    pool2 += __shfl_xor(pool2, m);
    pool3 += __shfl_xor(pool3, m);
  }
  if (r15 == 0) {
    float* dst = pool_part + (size_t)blk * 256 + chbase;
    dst[0] = pool0; dst[1] = pool1; dst[2] = pool2; dst[3] = pool3;
  }
}

// -------- kernel 2: tiny MLPs -> per-(b,c) 3x3 kernels + attn coefs --------
// grid 80 = 8 batches x 10 jobs (j=0..8: tap j of all 256 channels; j=9: coef)
__global__ __launch_bounds__(256) void k2_small(
    const float* __restrict__ pool_part,
    const float* __restrict__ w_cg1, const float* __restrict__ w_cg2,
    const float* __restrict__ w_ag1, const float* __restrict__ w_ag2,
    float* __restrict__ cw, float* __restrict__ coef)
{
  __shared__ float pl[256];
  __shared__ float hl[64];
  const int bi = blockIdx.x;
  const int b = bi / 10, j = bi % 10;
  const int t = threadIdx.x;
  float s = 0.f;
  const float* base = pool_part + (size_t)b * 32 * 256 + t;
  for (int blk = 0; blk < 32; ++blk) s += base[blk * 256];   // fixed order
  pl[t] = s * (1.0f / 16384.0f);
  __syncthreads();
  if (j < 9) {
    if (t < 64) {
      float h = 0.f;
      for (int i = 0; i < 256; ++i) h += pl[i] * w_cg1[t * 256 + i];
      hl[t] = fmaxf(h, 0.f);
    }
    __syncthreads();
    const int o = t * 9 + j;                 // row of w_cg2 = c*9 + tap
    float acc = 0.f;
    for (int jj = 0; jj < 64; ++jj) acc += hl[jj] * w_cg2[o * 64 + jj];
    cw[b * 2304 + o] = acc;
  } else {
    if (t < 64) {
      float a = 0.f;
      for (int i = 0; i < 256; ++i) a += pl[i] * w_ag1[t * 256 + i];
      hl[t] = fmaxf(a, 0.f);
    }
    __syncthreads();
    if (t < 2) {
      float acc = 0.f;
      for (int jj = 0; jj < 64; ++jj) acc += hl[jj] * w_ag2[t * 64 + jj];
      coef[b * 2 + t] = 0.25f / (1.0f + expf(-acc));   // 0.25 = L_S * L_C
    }
  }
}

// -------- kernel 3: depthwise 3x3 (same kernel on x1 & x2) + combine --------
__global__ __launch_bounds__(256) void k3_dynconv(
    const float* __restrict__ x1, const float* __restrict__ x2,
    const float* __restrict__ cw, const float* __restrict__ coef,
    float* __restrict__ out)
{
  __shared__ float t1[34 * 128];
  __shared__ float t2[34 * 128];
  const int tid   = threadIdx.x;
  const int blk   = blockIdx.x;
  const int strip = blk & 3;
  const int c     = (blk >> 2) & 255;
  const int b     = blk >> 10;
  const int h0    = strip * 32;

  const size_t plane = ((size_t)b * C_ + c) * HW_;
  const float* p1 = x1 + plane;
  const float* p2 = x2 + plane;

  float tp[9];
#pragma unroll
  for (int e = 0; e < 9; ++e) tp[e] = cw[(b * C_ + c) * 9 + e];
  const float c1 = coef[b * 2 + 0];
  const float c2 = coef[b * 2 + 1];

  for (int f = tid; f < 1088; f += 256) {
    int row = f >> 5;
    int c4  = (f & 31) << 2;
    int gh  = h0 - 1 + row;
    float4 v1 = make_float4(0.f, 0.f, 0.f, 0.f), v2 = v1;
    if (gh >= 0 && gh < 128) {
      v1 = *(const float4*)&p1[gh * 128 + c4];
      v2 = *(const float4*)&p2[gh * 128 + c4];
    }
    *(float4*)&t1[row * 128 + c4] = v1;
    *(float4*)&t2[row * 128 + c4] = v2;
  }
  __syncthreads();

  for (int i = 0; i < 16; ++i) {
    int q   = tid + i * 256;
    int r   = q >> 7;
    int col = q & 127;
    int lr  = r + 1;
    const bool lok = col > 0, rok = col < 127;
    float d1 = 0.f, d2 = 0.f;
#pragma unroll
    for (int dy = 0; dy < 3; ++dy) {
      const float* row1 = &t1[(lr - 1 + dy) * 128];
      const float* row2 = &t2[(lr - 1 + dy) * 128];
      float a1v = lok ? row1[col - 1] : 0.f;
      float b1v = row1[col];
      float e1v = rok ? row1[col + 1] : 0.f;
      float a2v = lok ? row2[col - 1] : 0.f;
      float b2v = row2[col];
      float e2v = rok ? row2[col + 1] : 0.f;
      d1 += a1v * tp[dy * 3 + 0] + b1v * tp[dy * 3 + 1] + e1v * tp[dy * 3 + 2];
      d2 += a2v * tp[dy * 3 + 0] + b2v * tp[dy * 3 + 1] + e2v * tp[dy * 3 + 2];
    }
    float v1 = t1[lr * 128 + col];
    float v2 = t2[lr * 128 + col];
    out[plane + (size_t)(h0 + r) * 128 + col] = 0.5f * (v1 + v2) + c1 * d1 + c2 * d2;
  }
}

extern "C" void kernel_launch(void* const* d_in, const int* in_sizes, int n_in,
                              void* d_out, int out_size, void* d_ws, size_t ws_size,
                              hipStream_t stream) {
  const float* x1    = (const float*)d_in[0];
  const float* x2    = (const float*)d_in[1];
  const float* w_fe  = (const float*)d_in[2];
  const float* gamma = (const float*)d_in[3];
  const float* beta  = (const float*)d_in[4];
  const float* mean  = (const float*)d_in[5];
  const float* var   = (const float*)d_in[6];
  const float* w_cg1 = (const float*)d_in[7];
  const float* w_cg2 = (const float*)d_in[8];
  const float* w_ag1 = (const float*)d_in[9];
  const float* w_ag2 = (const float*)d_in[10];
  float* out = (float*)d_out;

  // workspace layout (~470 KB)
  char* ws = (char*)d_ws;
  u32* Wp          = (u32*)(ws);                           // [0, 131072)
  float* scale     = (float*)(ws + 131072);                // 1 KB
  float* shift     = (float*)(ws + 132096);                // 1 KB
  float* pool_part = (float*)(ws + 133120);                // 256*256*4 = 256 KB
  float* cw        = (float*)(ws + 395264);                // 73728 B
  float* coef      = (float*)(ws + 468992);                // 64 B

  k0_prep<<<128, 256, 0, stream>>>(w_fe, gamma, beta, mean, var, Wp, scale, shift);
  k1_gemm_pool<<<256, 1024, 0, stream>>>(x1, x2, Wp, scale, shift, pool_part);
  k2_small<<<80, 256, 0, stream>>>(pool_part, w_cg1, w_cg2, w_ag1, w_ag2, cw, coef);
  k3_dynconv<<<8192, 256, 0, stream>>>(x1, x2, cw, coef, out);
}

// Round 16
// 241.339 us; speedup vs baseline: 1.0108x; 1.0048x over previous
//
#include <hip/hip_runtime.h>
#include <stdint.h>
#include <math.h>

#define HW_ 16384   // H*W = 128*128
#define C_  256
#define NT  2       // tiles per block (each tile = 256 positions)

typedef long i64;
typedef float f32x4 __attribute__((ext_vector_type(4)));
typedef unsigned int u32;
typedef unsigned long long u64;

// -------- kernel 0: prep (W -> fp8 e4m3 in MFMA-fragment order, BN consts) --
// Wp byte layout: idx = ((ks*16 + mf)*64 + kg*16 + r15)*8 + e
__global__ __launch_bounds__(256) void k0_prep(
    const float* __restrict__ w_fe, const float* __restrict__ gamma,
    const float* __restrict__ beta, const float* __restrict__ mean,
    const float* __restrict__ var, u32* __restrict__ Wp,
    float* __restrict__ scale, float* __restrict__ shift)
{
  int i = blockIdx.x * 256 + threadIdx.x;
  if (i < 32768) {                     // one u32 = 4 fp8 bytes
    int e0  = (i & 1) * 4;
    int r15 = (i >> 1) & 15;
    int kg  = (i >> 5) & 3;
    int mf  = (i >> 7) & 15;
    int ks  = i >> 11;
    int row = mf * 16 + r15;
    int k   = ks * 32 + kg * 8 + e0;   // 4 consecutive k
    const float* src = w_fe + row * 512 + k;
    u32 w = 0;
    w = __builtin_amdgcn_cvt_pk_fp8_f32(src[0], src[1], w, false);
    w = __builtin_amdgcn_cvt_pk_fp8_f32(src[2], src[3], w, true);
    Wp[i] = w;
  }
  if (i < 256) {
    float sc = gamma[i] * rsqrtf(var[i] + 1e-5f);
    scale[i] = sc;
    shift[i] = beta[i] - mean[i] * sc;
  }
}

// ------- kernel 1: persistent-W fp8 MFMA GEMM + BN + ReLU + pool -------
// 512 thr / launch_bounds(512,2) -> 256 regs/wave: the register space where
// 1-KB-contiguous staging CANNOT spill (Af 64 + g 32 + acc 32 + misc << 256).
// 8 waves; wave w owns m-frags {w, w+8}. Tile = 256 pos x 512 k fp8 in a
// single 128-KB LDS buffer (layout/algebra identical to R14/R15, verified).
// FILL: each wave-instruction reads ONE 1-KB contiguous k-row segment
// (64 lanes x float4) -- the same per-instruction shape as k3's streaming.
// Serial fill -> compute (compute ~10% of budget). Grid: 256 x 512.
__global__ __launch_bounds__(512, 2) void k1_gemm_pool(
    const float* __restrict__ x1, const float* __restrict__ x2,
    const u32* __restrict__ Wp,
    const float* __restrict__ scale, const float* __restrict__ shift,
    float* __restrict__ pool_part)
{
  __shared__ __align__(16) char Bl[131072];   // 64 row-octets x 2048 B

  const int tid  = threadIdx.x;
  const int wave = tid >> 6;        // 0..7
  const int lane = tid & 63;
  const int r15  = lane & 15;
  const int kg   = lane >> 4;
  const int blk  = blockIdx.x;
  const int b    = blk >> 5;                 // batch
  const int jp   = blk & 31;                 // tile-pair index

  const float* xb1 = x1 + (size_t)b * C_ * HW_;
  const float* xb2 = x2 + (size_t)b * C_ * HW_;

  // ---- A-frags for BOTH m-frags of this wave (32 x i64 = 64 regs) ----
  i64 Af[32];
#pragma unroll
  for (int h = 0; h < 2; ++h) {
    const int mf = wave + h * 8;
#pragma unroll
    for (int ks = 0; ks < 16; ++ks)
      Af[h * 16 + ks] = *(const i64*)((const char*)Wp
                        + ((ks * 16 + mf) * 64 + kg * 16 + r15) * 8);
  }

  const int chA = wave * 16 + kg * 4;
  const int chB = (wave + 8) * 16 + kg * 4;
  const float4 scA = *(const float4*)&scale[chA];
  const float4 shA = *(const float4*)&shift[chA];
  const float4 scB = *(const float4*)&scale[chB];
  const float4 shB = *(const float4*)&shift[chB];

  float pA0 = 0.f, pA1 = 0.f, pA2 = 0.f, pA3 = 0.f;
  float pB0 = 0.f, pB1 = 0.f, pB2 = 0.f, pB3 = 0.f;

  for (int tt = 0; tt < NT; ++tt) {
    const int P0 = (jp * NT + tt) * 256;   // tile base position

    // ========== FILL: 512 rows x 1-KB contiguous wave-loads =============
    // wave w stages row-octets {w, w+8, ..., w+56}; one g[8] (32 regs) live.
#pragma unroll 1
    for (int gi = 0; gi < 8; ++gi) {
      const int G = wave + gi * 8;         // row-octet 0..63 (wave-uniform)
      const float* src = ((G < 32) ? (xb1 + (size_t)(G * 8) * HW_)
                                   : (xb2 + (size_t)((G - 32) * 8) * HW_))
                         + P0 + lane * 4;
      f32x4 g[8];
#pragma unroll
      for (int j = 0; j < 8; ++j) g[j] = *(const f32x4*)(src + (size_t)j * HW_);
      char* rowb = Bl + G * 2048;
#pragma unroll
      for (int q2 = 0; q2 < 4; ++q2) {
        u32 w0 = 0, w1 = 0;
        w0 = __builtin_amdgcn_cvt_pk_fp8_f32(g[0][q2], g[1][q2], w0, false);
        w0 = __builtin_amdgcn_cvt_pk_fp8_f32(g[2][q2], g[3][q2], w0, true);
        w1 = __builtin_amdgcn_cvt_pk_fp8_f32(g[4][q2], g[5][q2], w1, false);
        w1 = __builtin_amdgcn_cvt_pk_fp8_f32(g[6][q2], g[7][q2], w1, true);
        int p  = lane * 4 + q2;
        int sl = p ^ ((p >> 4) & 3) ^ ((G & 3) << 4);
        u64 v = (u64)w0 | ((u64)w1 << 32);   // bytes e0..e7
        *(u64*)(rowb + sl * 8) = v;
      }
      __builtin_amdgcn_sched_barrier(0);     // one staging bank live at a time
    }
    __syncthreads();   // tile staged

    // ========== COMPUTE: 2 m-frags x 2 passes x (16 ks x 8 nf) ==========
    // read slot decodes to logical pos = nf*16 + r15 (verified bijective).
#pragma unroll
    for (int h = 0; h < 2; ++h) {
#pragma unroll
      for (int pass = 0; pass < 2; ++pass) {
        f32x4 acc[8];
#pragma unroll
        for (int f = 0; f < 8; ++f) acc[f] = (f32x4){0.f, 0.f, 0.f, 0.f};
#pragma unroll
        for (int ks = 0; ks < 16; ++ks) {
          const char* kb = Bl + ks * 8192 + kg * 2048;
#pragma unroll
          for (int f = 0; f < 8; ++f) {
            const int nf = pass * 8 + f;
            const int sl = (((nf ^ kg) & 15) << 4) | (r15 ^ (nf & 3));
            i64 bq = *(const i64*)(kb + sl * 8);
            acc[f] = __builtin_amdgcn_mfma_f32_16x16x32_fp8_fp8(
                Af[h * 16 + ks], bq, acc[f], 0, 0, 0);
          }
        }
        // BN + ReLU + pool over these 128 positions
        if (h == 0) {
#pragma unroll
          for (int f = 0; f < 8; ++f) {
            pA0 += fmaxf(acc[f][0] * scA.x + shA.x, 0.f);
            pA1 += fmaxf(acc[f][1] * scA.y + shA.y, 0.f);
            pA2 += fmaxf(acc[f][2] * scA.z + shA.z, 0.f);
            pA3 += fmaxf(acc[f][3] * scA.w + shA.w, 0.f);
          }
        } else {
#pragma unroll
          for (int f = 0; f < 8; ++f) {
            pB0 += fmaxf(acc[f][0] * scB.x + shB.x, 0.f);
            pB1 += fmaxf(acc[f][1] * scB.y + shB.y, 0.f);
            pB2 += fmaxf(acc[f][2] * scB.z + shB.z, 0.f);
            pB3 += fmaxf(acc[f][3] * scB.w + shB.w, 0.f);
          }
        }
      }
    }
    __syncthreads();   // all waves done reading before next fill
  }

  // reduce over the 16 positions (r15 lanes)
#pragma unroll
  for (int m = 1; m < 16; m <<= 1) {
    pA0 += __shfl_xor(pA0, m); pA1 += __shfl_xor(pA1, m);
    pA2 += __shfl_xor(pA2, m); pA3 += __shfl_xor(pA3, m);
    pB0 += __shfl_xor(pB0, m); pB1 += __shfl_xor(pB1, m);
    pB2 += __shfl_xor(pB2, m); pB3 += __shfl_xor(pB3, m);
  }
  if (r15 == 0) {
    float* dA = pool_part + (size_t)blk * 256 + chA;
    dA[0] = pA0; dA[1] = pA1; dA[2] = pA2; dA[3] = pA3;
    float* dB = pool_part + (size_t)blk * 256 + chB;
    dB[0] = pB0; dB[1] = pB1; dB[2] = pB2; dB[3] = pB3;
  }
}

// -------- kernel 2: tiny MLPs -> per-(b,c) 3x3 kernels + attn coefs --------
// grid 80 = 8 batches x 10 jobs (j=0..8: tap j of all 256 channels; j=9: coef)
__global__ __launch_bounds__(256) void k2_small(
    const float* __restrict__ pool_part,
    const float* __restrict__ w_cg1, const float* __restrict__ w_cg2,
    const float* __restrict__ w_ag1, const float* __restrict__ w_ag2,
    float* __restrict__ cw, float* __restrict__ coef)
{
  __shared__ float pl[256];
  __shared__ float hl[64];
  const int bi = blockIdx.x;
  const int b = bi / 10, j = bi % 10;
  const int t = threadIdx.x;
  float s = 0.f;
  const float* base = pool_part + (size_t)b * 32 * 256 + t;
  for (int blk = 0; blk < 32; ++blk) s += base[blk * 256];   // fixed order
  pl[t] = s * (1.0f / 16384.0f);
  __syncthreads();
  if (j < 9) {
    if (t < 64) {
      float h = 0.f;
      for (int i = 0; i < 256; ++i) h += pl[i] * w_cg1[t * 256 + i];
      hl[t] = fmaxf(h, 0.f);
    }
    __syncthreads();
    const int o = t * 9 + j;                 // row of w_cg2 = c*9 + tap
    float acc = 0.f;
    for (int jj = 0; jj < 64; ++jj) acc += hl[jj] * w_cg2[o * 64 + jj];
    cw[b * 2304 + o] = acc;
  } else {
    if (t < 64) {
      float a = 0.f;
      for (int i = 0; i < 256; ++i) a += pl[i] * w_ag1[t * 256 + i];
      hl[t] = fmaxf(a, 0.f);
    }
    __syncthreads();
    if (t < 2) {
      float acc = 0.f;
      for (int jj = 0; jj < 64; ++jj) acc += hl[jj] * w_ag2[t * 64 + jj];
      coef[b * 2 + t] = 0.25f / (1.0f + expf(-acc));   // 0.25 = L_S * L_C
    }
  }
}

// -------- kernel 3: depthwise 3x3 (same kernel on x1 & x2) + combine --------
__global__ __launch_bounds__(256) void k3_dynconv(
    const float* __restrict__ x1, const float* __restrict__ x2,
    const float* __restrict__ cw, const float* __restrict__ coef,
    float* __restrict__ out)
{
  __shared__ float t1[34 * 128];
  __shared__ float t2[34 * 128];
  const int tid   = threadIdx.x;
  const int blk   = blockIdx.x;
  const int strip = blk & 3;
  const int c     = (blk >> 2) & 255;
  const int b     = blk >> 10;
  const int h0    = strip * 32;

  const size_t plane = ((size_t)b * C_ + c) * HW_;
  const float* p1 = x1 + plane;
  const float* p2 = x2 + plane;

  float tp[9];
#pragma unroll
  for (int e = 0; e < 9; ++e) tp[e] = cw[(b * C_ + c) * 9 + e];
  const float c1 = coef[b * 2 + 0];
  const float c2 = coef[b * 2 + 1];

  for (int f = tid; f < 1088; f += 256) {
    int row = f >> 5;
    int c4  = (f & 31) << 2;
    int gh  = h0 - 1 + row;
    float4 v1 = make_float4(0.f, 0.f, 0.f, 0.f), v2 = v1;
    if (gh >= 0 && gh < 128) {
      v1 = *(const float4*)&p1[gh * 128 + c4];
      v2 = *(const float4*)&p2[gh * 128 + c4];
    }
    *(float4*)&t1[row * 128 + c4] = v1;
    *(float4*)&t2[row * 128 + c4] = v2;
  }
  __syncthreads();

  for (int i = 0; i < 16; ++i) {
    int q   = tid + i * 256;
    int r   = q >> 7;
    int col = q & 127;
    int lr  = r + 1;
    const bool lok = col > 0, rok = col < 127;
    float d1 = 0.f, d2 = 0.f;
#pragma unroll
    for (int dy = 0; dy < 3; ++dy) {
      const float* row1 = &t1[(lr - 1 + dy) * 128];
      const float* row2 = &t2[(lr - 1 + dy) * 128];
      float a1v = lok ? row1[col - 1] : 0.f;
      float b1v = row1[col];
      float e1v = rok ? row1[col + 1] : 0.f;
      float a2v = lok ? row2[col - 1] : 0.f;
      float b2v = row2[col];
      float e2v = rok ? row2[col + 1] : 0.f;
      d1 += a1v * tp[dy * 3 + 0] + b1v * tp[dy * 3 + 1] + e1v * tp[dy * 3 + 2];
      d2 += a2v * tp[dy * 3 + 0] + b2v * tp[dy * 3 + 1] + e2v * tp[dy * 3 + 2];
    }
    float v1 = t1[lr * 128 + col];
    float v2 = t2[lr * 128 + col];
    out[plane + (size_t)(h0 + r) * 128 + col] = 0.5f * (v1 + v2) + c1 * d1 + c2 * d2;
  }
}

extern "C" void kernel_launch(void* const* d_in, const int* in_sizes, int n_in,
                              void* d_out, int out_size, void* d_ws, size_t ws_size,
                              hipStream_t stream) {
  const float* x1    = (const float*)d_in[0];
  const float* x2    = (const float*)d_in[1];
  const float* w_fe  = (const float*)d_in[2];
  const float* gamma = (const float*)d_in[3];
  const float* beta  = (const float*)d_in[4];
  const float* mean  = (const float*)d_in[5];
  const float* var   = (const float*)d_in[6];
  const float* w_cg1 = (const float*)d_in[7];
  const float* w_cg2 = (const float*)d_in[8];
  const float* w_ag1 = (const float*)d_in[9];
  const float* w_ag2 = (const float*)d_in[10];
  float* out = (float*)d_out;

  // workspace layout (~470 KB)
  char* ws = (char*)d_ws;
  u32* Wp          = (u32*)(ws);                           // [0, 131072)
  float* scale     = (float*)(ws + 131072);                // 1 KB
  float* shift     = (float*)(ws + 132096);                // 1 KB
  float* pool_part = (float*)(ws + 133120);                // 256*256*4 = 256 KB
  float* cw        = (float*)(ws + 395264);                // 73728 B
  float* coef      = (float*)(ws + 468992);                // 64 B

  k0_prep<<<128, 256, 0, stream>>>(w_fe, gamma, beta, mean, var, Wp, scale, shift);
  k1_gemm_pool<<<256, 512, 0, stream>>>(x1, x2, Wp, scale, shift, pool_part);
  k2_small<<<80, 256, 0, stream>>>(pool_part, w_cg1, w_cg2, w_ag1, w_ag2, cw, coef);
  k3_dynconv<<<8192, 256, 0, stream>>>(x1, x2, cw, coef, out);
}

// Round 17
// 195.477 us; speedup vs baseline: 1.2479x; 1.2346x over previous
//
#include <hip/hip_runtime.h>
#include <stdint.h>
#include <math.h>

#define HW_ 16384   // H*W = 128*128
#define C_  256
#define NT  4       // tiles per block (each tile = 128 positions)

typedef long i64;
typedef float f32x4 __attribute__((ext_vector_type(4)));
typedef unsigned int u32;

// barrier WITHOUT vmcnt drain: orders LDS only; prefetch loads stay in flight
#define BARRIER_LGKM() asm volatile("s_waitcnt lgkmcnt(0)\n\ts_barrier" ::: "memory")

// -------- kernel 0: prep (W -> fp8 e4m3 in MFMA-fragment order, BN consts) --
// Wp byte layout: idx = ((ks*16 + mf)*64 + kg*16 + r15)*8 + e
__global__ __launch_bounds__(256) void k0_prep(
    const float* __restrict__ w_fe, const float* __restrict__ gamma,
    const float* __restrict__ beta, const float* __restrict__ mean,
    const float* __restrict__ var, u32* __restrict__ Wp,
    float* __restrict__ scale, float* __restrict__ shift)
{
  int i = blockIdx.x * 256 + threadIdx.x;
  if (i < 32768) {                     // one u32 = 4 fp8 bytes
    int e0  = (i & 1) * 4;
    int r15 = (i >> 1) & 15;
    int kg  = (i >> 5) & 3;
    int mf  = (i >> 7) & 15;
    int ks  = i >> 11;
    int row = mf * 16 + r15;
    int k   = ks * 32 + kg * 8 + e0;   // 4 consecutive k
    const float* src = w_fe + row * 512 + k;
    u32 w = 0;
    w = __builtin_amdgcn_cvt_pk_fp8_f32(src[0], src[1], w, false);
    w = __builtin_amdgcn_cvt_pk_fp8_f32(src[2], src[3], w, true);
    Wp[i] = w;
  }
  if (i < 256) {
    float sc = gamma[i] * rsqrtf(var[i] + 1e-5f);
    scale[i] = sc;
    shift[i] = beta[i] - mean[i] * sc;
  }
}

// ------- kernel q8: streaming quantize X -> X8 (fp8, row-major) -------
// X8 layout: [b][512 rows][16384 pos]; rows 0-255 = x1 ch, 256-511 = x2 ch.
// Pure elementwise; every wave-load is 4KB contiguous. Read 268MB, write 67MB.
__global__ __launch_bounds__(256) void kq8(
    const float* __restrict__ x1, const float* __restrict__ x2,
    u32* __restrict__ X8)
{
  const size_t g = (size_t)blockIdx.x * 256 + threadIdx.x;  // 16-float granule
  const int R   = (int)(g >> 10);        // global row 0..4095
  const int b   = R >> 9;
  const int r   = R & 511;
  const int pos = (int)(g & 1023) << 4;
  const float* src = ((r < 256) ? (x1 + ((size_t)(b * 256 + r) << 14))
                                : (x2 + ((size_t)(b * 256 + r - 256) << 14)))
                     + pos;
  u32 o0, o1, o2, o3;
  {
    f32x4 v;
    v = *(const f32x4*)(src);
    o0 = __builtin_amdgcn_cvt_pk_fp8_f32(v[0], v[1], 0u, false);
    o0 = __builtin_amdgcn_cvt_pk_fp8_f32(v[2], v[3], o0, true);
    v = *(const f32x4*)(src + 4);
    o1 = __builtin_amdgcn_cvt_pk_fp8_f32(v[0], v[1], 0u, false);
    o1 = __builtin_amdgcn_cvt_pk_fp8_f32(v[2], v[3], o1, true);
    v = *(const f32x4*)(src + 8);
    o2 = __builtin_amdgcn_cvt_pk_fp8_f32(v[0], v[1], 0u, false);
    o2 = __builtin_amdgcn_cvt_pk_fp8_f32(v[2], v[3], o2, true);
    v = *(const f32x4*)(src + 12);
    o3 = __builtin_amdgcn_cvt_pk_fp8_f32(v[0], v[1], 0u, false);
    o3 = __builtin_amdgcn_cvt_pk_fp8_f32(v[2], v[3], o3, true);
  }
  u32* dst = (u32*)((char*)X8 + (((size_t)R) << 14) + pos);
  dst[0] = o0; dst[1] = o1; dst[2] = o2; dst[3] = o3;
}

// ------- kernel 1q: fp8-gather MFMA GEMM + BN + ReLU + pool -------
// EXACTLY R12's structure/LDS algebra, but the gather reads fp8 X8 (67MB,
// 4x fewer bytes through the byte-rate-capped strided path).
__global__ __launch_bounds__(1024, 4) void k1q(
    const char* __restrict__ X8, const u32* __restrict__ Wp,
    const float* __restrict__ scale, const float* __restrict__ shift,
    float* __restrict__ pool_part)
{
  __shared__ __align__(16) char Bl[2][65536];   // 2 x 64KB

  const int tid  = threadIdx.x;
  const int wave = tid >> 6;        // = mf
  const int lane = tid & 63;
  const int r15  = lane & 15;
  const int kg   = lane >> 4;
  const int blk  = blockIdx.x;
  const int b    = blk >> 5;                 // batch
  const int t0   = (blk & 31) * NT;

  const char* Xb = X8 + ((size_t)b << 23);   // this batch's 512 rows

  const int o   = tid >> 5;          // 0..31 octet within half
  const int q   = tid & 31;          // pos-quad
  const int pq  = q * 4;             // pos base 0..124
  const int wq  = (q * 32) ^ ((o & 3) << 5);
  const int rb_off = (r15 * 8) ^ (kg << 5);

  // ---- A-frags once for this wave (16 x i64 = 32 regs) ----
  i64 Af[16];
#pragma unroll
  for (int ks = 0; ks < 16; ++ks)
    Af[ks] = *(const i64*)((const char*)Wp
             + ((ks * 16 + wave) * 64 + kg * 16 + r15) * 8);

  const int chbase = wave * 16 + kg * 4;
  const float4 sc4 = *(const float4*)&scale[chbase];
  const float4 sh4 = *(const float4*)&shift[chbase];

  float pool0 = 0.f, pool1 = 0.f, pool2 = 0.f, pool3 = 0.f;

  u32 gq[4];   // staging sub-unit: 4 rows x 4 pos (4 regs)

#define ISSUE_U(H, S, P0)                                                     \
  {                                                                           \
    const char* s0 = Xb + (((size_t)((H) * 256 + o * 8 + (S) * 4)) << 14)     \
                     + (P0) + pq;                                             \
    _Pragma("unroll")                                                         \
    for (int r = 0; r < 4; ++r) gq[r] = *(const u32*)(s0 + ((size_t)r << 14));\
  }

#define WRITE_U(H, S, BUF)                                                    \
  {                                                                           \
    char* wb = (char*)(BUF) + ((H) * 32 + o) * 1024 + wq + (S) * 4;           \
    _Pragma("unroll")                                                         \
    for (int j = 0; j < 4; ++j) {                                             \
      u32 w = ((gq[0] >> (8 * j)) & 0xffu)                                    \
            | (((gq[1] >> (8 * j)) & 0xffu) << 8)                             \
            | (((gq[2] >> (8 * j)) & 0xffu) << 16)                            \
            | (((gq[3] >> (8 * j)) & 0xffu) << 24);                           \
      *(u32*)(wb + j * 8) = w;                                                \
    }                                                                         \
  }

#define COMPUTE_Q(QK, BUF)                                                    \
  {                                                                           \
    _Pragma("unroll")                                                         \
    for (int ks = (QK) * 4; ks < (QK) * 4 + 4; ++ks) {                        \
      const char* rb = (const char*)(BUF) + (ks * 4 + kg) * 1024 + rb_off;    \
      _Pragma("unroll")                                                       \
      for (int nf = 0; nf < 8; ++nf) {                                        \
        i64 bq = *(const i64*)(rb + nf * 128);                                \
        acc[nf] = __builtin_amdgcn_mfma_f32_16x16x32_fp8_fp8(                 \
            Af[ks], bq, acc[nf], 0, 0, 0);                                    \
      }                                                                       \
    }                                                                         \
  }

  ISSUE_U(0, 0, t0 * 128) WRITE_U(0, 0, Bl[0])
  ISSUE_U(0, 1, t0 * 128) WRITE_U(0, 1, Bl[0])
  ISSUE_U(1, 0, t0 * 128) WRITE_U(1, 0, Bl[0])
  ISSUE_U(1, 1, t0 * 128) WRITE_U(1, 1, Bl[0])
  __syncthreads();

  for (int tt = 0; tt < NT; ++tt) {
    f32x4 acc[8];
#pragma unroll
    for (int nf = 0; nf < 8; ++nf) acc[nf] = (f32x4){0.f, 0.f, 0.f, 0.f};

    const int p1 = (t0 + tt + 1) * 128;
    const bool more = (tt + 1 < NT);
    const char* cb = Bl[tt & 1];
    char* nxt = Bl[(tt + 1) & 1];

    if (more) ISSUE_U(0, 0, p1)
    COMPUTE_Q(0, cb)
    if (more) { WRITE_U(0, 0, nxt) ISSUE_U(0, 1, p1) }
    COMPUTE_Q(1, cb)
    if (more) { WRITE_U(0, 1, nxt) ISSUE_U(1, 0, p1) }
    COMPUTE_Q(2, cb)
    if (more) { WRITE_U(1, 0, nxt) ISSUE_U(1, 1, p1) }
    COMPUTE_Q(3, cb)
    if (more) WRITE_U(1, 1, nxt)

#pragma unroll
    for (int nf = 0; nf < 8; ++nf) {
      pool0 += fmaxf(acc[nf][0] * sc4.x + sh4.x, 0.f);
      pool1 += fmaxf(acc[nf][1] * sc4.y + sh4.y, 0.f);
      pool2 += fmaxf(acc[nf][2] * sc4.z + sh4.z, 0.f);
      pool3 += fmaxf(acc[nf][3] * sc4.w + sh4.w, 0.f);
    }
    BARRIER_LGKM();
  }

#pragma unroll
  for (int m = 1; m < 16; m <<= 1) {
    pool0 += __shfl_xor(pool0, m);
    pool1 += __shfl_xor(pool1, m);
    pool2 += __shfl_xor(pool2, m);
    pool3 += __shfl_xor(pool3, m);
  }
  if (r15 == 0) {
    float* dst = pool_part + (size_t)blk * 256 + chbase;
    dst[0] = pool0; dst[1] = pool1; dst[2] = pool2; dst[3] = pool3;
  }
}

// ------- kernel 1 FALLBACK: R12 k1 verbatim (f32 gather) -------
__global__ __launch_bounds__(1024, 4) void k1_fb(
    const float* __restrict__ x1, const float* __restrict__ x2,
    const u32* __restrict__ Wp,
    const float* __restrict__ scale, const float* __restrict__ shift,
    float* __restrict__ pool_part)
{
  __shared__ __align__(16) char Bl[2][65536];
  const int tid  = threadIdx.x;
  const int wave = tid >> 6;
  const int lane = tid & 63;
  const int r15  = lane & 15;
  const int kg   = lane >> 4;
  const int blk  = blockIdx.x;
  const int b    = blk >> 5;
  const int t0   = (blk & 31) * NT;
  const float* xb1 = x1 + (size_t)b * C_ * HW_;
  const float* xb2 = x2 + (size_t)b * C_ * HW_;
  const int o   = tid >> 5;
  const int q   = tid & 31;
  const int pq  = q * 4;
  const int wq  = (q * 32) ^ ((o & 3) << 5);
  const int rb_off = (r15 * 8) ^ (kg << 5);
  i64 Af[16];
#pragma unroll
  for (int ks = 0; ks < 16; ++ks)
    Af[ks] = *(const i64*)((const char*)Wp
             + ((ks * 16 + wave) * 64 + kg * 16 + r15) * 8);
  const int chbase = wave * 16 + kg * 4;
  const float4 sc4 = *(const float4*)&scale[chbase];
  const float4 sh4 = *(const float4*)&shift[chbase];
  float pool0 = 0.f, pool1 = 0.f, pool2 = 0.f, pool3 = 0.f;
  f32x4 gU[4];
#define FISSUE(H, S, P0)                                                      \
  { const float* s0 = ((H) == 0 ? xb1 : xb2)                                  \
                      + (size_t)(o * 8 + (S) * 4) * HW_ + (P0) + pq;          \
    _Pragma("unroll")                                                         \
    for (int r = 0; r < 4; ++r) gU[r] = *(const f32x4*)(s0 + r * HW_); }
#define FWRITE(H, S, BUF)                                                     \
  { char* wb = (char*)(BUF) + ((H) * 32 + o) * 1024 + wq + (S) * 4;           \
    _Pragma("unroll")                                                         \
    for (int j = 0; j < 4; ++j) {                                             \
      u32 w = 0;                                                              \
      w = __builtin_amdgcn_cvt_pk_fp8_f32(gU[0][j], gU[1][j], w, false);      \
      w = __builtin_amdgcn_cvt_pk_fp8_f32(gU[2][j], gU[3][j], w, true);       \
      *(u32*)(wb + j * 8) = w; } }
#define FCOMP(QK, BUF)                                                        \
  { _Pragma("unroll")                                                         \
    for (int ks = (QK) * 4; ks < (QK) * 4 + 4; ++ks) {                        \
      const char* rb = (const char*)(BUF) + (ks * 4 + kg) * 1024 + rb_off;    \
      _Pragma("unroll")                                                       \
      for (int nf = 0; nf < 8; ++nf) {                                        \
        i64 bq = *(const i64*)(rb + nf * 128);                                \
        acc[nf] = __builtin_amdgcn_mfma_f32_16x16x32_fp8_fp8(                 \
            Af[ks], bq, acc[nf], 0, 0, 0); } } }
  FISSUE(0, 0, t0 * 128) FWRITE(0, 0, Bl[0])
  FISSUE(0, 1, t0 * 128) FWRITE(0, 1, Bl[0])
  FISSUE(1, 0, t0 * 128) FWRITE(1, 0, Bl[0])
  FISSUE(1, 1, t0 * 128) FWRITE(1, 1, Bl[0])
  __syncthreads();
  for (int tt = 0; tt < NT; ++tt) {
    f32x4 acc[8];
#pragma unroll
    for (int nf = 0; nf < 8; ++nf) acc[nf] = (f32x4){0.f, 0.f, 0.f, 0.f};
    const int p1 = (t0 + tt + 1) * 128;
    const bool more = (tt + 1 < NT);
    const char* cb = Bl[tt & 1];
    char* nxt = Bl[(tt + 1) & 1];
    if (more) FISSUE(0, 0, p1)
    FCOMP(0, cb)
    if (more) { FWRITE(0, 0, nxt) FISSUE(0, 1, p1) }
    FCOMP(1, cb)
    if (more) { FWRITE(0, 1, nxt) FISSUE(1, 0, p1) }
    FCOMP(2, cb)
    if (more) { FWRITE(1, 0, nxt) FISSUE(1, 1, p1) }
    FCOMP(3, cb)
    if (more) FWRITE(1, 1, nxt)
#pragma unroll
    for (int nf = 0; nf < 8; ++nf) {
      pool0 += fmaxf(acc[nf][0] * sc4.x + sh4.x, 0.f);
      pool1 += fmaxf(acc[nf][1] * sc4.y + sh4.y, 0.f);
      pool2 += fmaxf(acc[nf][2] * sc4.z + sh4.z, 0.f);
      pool3 += fmaxf(acc[nf][3] * sc4.w + sh4.w, 0.f);
    }
    BARRIER_LGKM();
  }
#pragma unroll
  for (int m = 1; m < 16; m <<= 1) {
    pool0 += __shfl_xor(pool0, m);
    pool1 += __shfl_xor(pool1, m);
    pool2 += __shfl_xor(pool2, m);
    pool3 += __shfl_xor(pool3, m);
  }
  if (r15 == 0) {
    float* dst = pool_part + (size_t)blk * 256 + chbase;
    dst[0] = pool0; dst[1] = pool1; dst[2] = pool2; dst[3] = pool3;
  }
}

// -------- kernel 2: tiny MLPs -> per-(b,c) 3x3 kernels + attn coefs --------
__global__ __launch_bounds__(256) void k2_small(
    const float* __restrict__ pool_part,
    const float* __restrict__ w_cg1, const float* __restrict__ w_cg2,
    const float* __restrict__ w_ag1, const float* __restrict__ w_ag2,
    float* __restrict__ cw, float* __restrict__ coef)
{
  __shared__ float pl[256];
  __shared__ float hl[64];
  const int bi = blockIdx.x;
  const int b = bi / 10, j = bi % 10;
  const int t = threadIdx.x;
  float s = 0.f;
  const float* base = pool_part + (size_t)b * 32 * 256 + t;
  for (int blk = 0; blk < 32; ++blk) s += base[blk * 256];   // fixed order
  pl[t] = s * (1.0f / 16384.0f);
  __syncthreads();
  if (j < 9) {
    if (t < 64) {
      float h = 0.f;
      for (int i = 0; i < 256; ++i) h += pl[i] * w_cg1[t * 256 + i];
      hl[t] = fmaxf(h, 0.f);
    }
    __syncthreads();
    const int o = t * 9 + j;
    float acc = 0.f;
    for (int jj = 0; jj < 64; ++jj) acc += hl[jj] * w_cg2[o * 64 + jj];
    cw[b * 2304 + o] = acc;
  } else {
    if (t < 64) {
      float a = 0.f;
      for (int i = 0; i < 256; ++i) a += pl[i] * w_ag1[t * 256 + i];
      hl[t] = fmaxf(a, 0.f);
    }
    __syncthreads();
    if (t < 2) {
      float acc = 0.f;
      for (int jj = 0; jj < 64; ++jj) acc += hl[jj] * w_ag2[t * 64 + jj];
      coef[b * 2 + t] = 0.25f / (1.0f + expf(-acc));   // 0.25 = L_S * L_C
    }
  }
}

// -------- kernel 3: depthwise 3x3 (same kernel on x1 & x2) + combine --------
__global__ __launch_bounds__(256) void k3_dynconv(
    const float* __restrict__ x1, const float* __restrict__ x2,
    const float* __restrict__ cw, const float* __restrict__ coef,
    float* __restrict__ out)
{
  __shared__ float t1[34 * 128];
  __shared__ float t2[34 * 128];
  const int tid   = threadIdx.x;
  const int blk   = blockIdx.x;
  const int strip = blk & 3;
  const int c     = (blk >> 2) & 255;
  const int b     = blk >> 10;
  const int h0    = strip * 32;

  const size_t plane = ((size_t)b * C_ + c) * HW_;
  const float* p1 = x1 + plane;
  const float* p2 = x2 + plane;

  float tp[9];
#pragma unroll
  for (int e = 0; e < 9; ++e) tp[e] = cw[(b * C_ + c) * 9 + e];
  const float c1 = coef[b * 2 + 0];
  const float c2 = coef[b * 2 + 1];

  for (int f = tid; f < 1088; f += 256) {
    int row = f >> 5;
    int c4  = (f & 31) << 2;
    int gh  = h0 - 1 + row;
    float4 v1 = make_float4(0.f, 0.f, 0.f, 0.f), v2 = v1;
    if (gh >= 0 && gh < 128) {
      v1 = *(const float4*)&p1[gh * 128 + c4];
      v2 = *(const float4*)&p2[gh * 128 + c4];
    }
    *(float4*)&t1[row * 128 + c4] = v1;
    *(float4*)&t2[row * 128 + c4] = v2;
  }
  __syncthreads();

  for (int i = 0; i < 16; ++i) {
    int q   = tid + i * 256;
    int r   = q >> 7;
    int col = q & 127;
    int lr  = r + 1;
    const bool lok = col > 0, rok = col < 127;
    float d1 = 0.f, d2 = 0.f;
#pragma unroll
    for (int dy = 0; dy < 3; ++dy) {
      const float* row1 = &t1[(lr - 1 + dy) * 128];
      const float* row2 = &t2[(lr - 1 + dy) * 128];
      float a1v = lok ? row1[col - 1] : 0.f;
      float b1v = row1[col];
      float e1v = rok ? row1[col + 1] : 0.f;
      float a2v = lok ? row2[col - 1] : 0.f;
      float b2v = row2[col];
      float e2v = rok ? row2[col + 1] : 0.f;
      d1 += a1v * tp[dy * 3 + 0] + b1v * tp[dy * 3 + 1] + e1v * tp[dy * 3 + 2];
      d2 += a2v * tp[dy * 3 + 0] + b2v * tp[dy * 3 + 1] + e2v * tp[dy * 3 + 2];
    }
    float v1 = t1[lr * 128 + col];
    float v2 = t2[lr * 128 + col];
    out[plane + (size_t)(h0 + r) * 128 + col] = 0.5f * (v1 + v2) + c1 * d1 + c2 * d2;
  }
}

extern "C" void kernel_launch(void* const* d_in, const int* in_sizes, int n_in,
                              void* d_out, int out_size, void* d_ws, size_t ws_size,
                              hipStream_t stream) {
  const float* x1    = (const float*)d_in[0];
  const float* x2    = (const float*)d_in[1];
  const float* w_fe  = (const float*)d_in[2];
  const float* gamma = (const float*)d_in[3];
  const float* beta  = (const float*)d_in[4];
  const float* mean  = (const float*)d_in[5];
  const float* var   = (const float*)d_in[6];
  const float* w_cg1 = (const float*)d_in[7];
  const float* w_cg2 = (const float*)d_in[8];
  const float* w_ag1 = (const float*)d_in[9];
  const float* w_ag2 = (const float*)d_in[10];
  float* out = (float*)d_out;

  char* ws = (char*)d_ws;
  u32* Wp          = (u32*)(ws);                           // [0, 131072)
  float* scale     = (float*)(ws + 131072);                // 1 KB
  float* shift     = (float*)(ws + 132096);                // 1 KB
  float* pool_part = (float*)(ws + 133120);                // 256 KB
  float* cw        = (float*)(ws + 395264);                // 73728 B
  float* coef      = (float*)(ws + 468992);                // 64 B
  char* X8         = ws + 524288;                          // 67,108,864 B
  const size_t NEED = 524288 + (size_t)8 * 512 * 16384;    // 67,633,152

  k0_prep<<<128, 256, 0, stream>>>(w_fe, gamma, beta, mean, var, Wp, scale, shift);
  if (ws_size >= NEED) {
    kq8<<<16384, 256, 0, stream>>>(x1, x2, (u32*)X8);
    k1q<<<256, 1024, 0, stream>>>(X8, Wp, scale, shift, pool_part);
  } else {
    k1_fb<<<256, 1024, 0, stream>>>(x1, x2, Wp, scale, shift, pool_part);
  }
  k2_small<<<80, 256, 0, stream>>>(pool_part, w_cg1, w_cg2, w_ag1, w_ag2, cw, coef);
  k3_dynconv<<<8192, 256, 0, stream>>>(x1, x2, cw, coef, out);
}